// Round 3
// baseline (226.378 us; speedup 1.0000x reference)
//
#include <hip/hip_runtime.h>
#include <float.h>
#include <math.h>

#define EPS 1e-6f

typedef __attribute__((ext_vector_type(8))) short short8;   // 8 bf16 = 4 VGPR
typedef __attribute__((ext_vector_type(4))) float f32x4;

constexpr int Nn = 8192;   // B*H*W
constexpr int Dd = 64;
constexpr int Kk = 8192;
constexpr int PLANE = Nn * Dd;            // elements per split plane (=Kk*Dd too)
constexpr int KSPLIT = 8;
constexpr int KPB = Kk / KSPLIT;          // 1024 codewords per block
constexpr int NTILES = KPB / 16;          // 64 n-tiles per wave

// exact 3-way bf16 split: v == f(h1)+f(h2)+f(h3) (24 mantissa bits, lossless)
__device__ inline void split3(float v, unsigned short& h1, unsigned short& h2, unsigned short& h3) {
    unsigned u = __float_as_uint(v);
    h1 = (unsigned short)(u >> 16);
    float r1 = v - __uint_as_float((unsigned)h1 << 16);
    h2 = (unsigned short)(__float_as_uint(r1) >> 16);
    float r2 = r1 - __uint_as_float((unsigned)h2 << 16);
    h3 = (unsigned short)(__float_as_uint(r2) >> 16);
}

// ---- prep: e (64,8192) -> es[k][d] bf16 x3 planes, en2h[k] = 0.5*||e_k||^2 ----
__global__ void prep_e(const float* __restrict__ e, unsigned short* __restrict__ es,
                       float* __restrict__ en2h) {
    int k = blockIdx.x * blockDim.x + threadIdx.x;
    if (k >= Kk) return;
    unsigned short* o = es + k * Dd;
    float s = 0.f;
    #pragma unroll 8
    for (int d = 0; d < Dd; ++d) {
        float v = e[d * Kk + k];          // coalesced across threads
        s = fmaf(v, v, s);
        unsigned short h1, h2, h3;
        split3(v, h1, h2, h3);
        o[d] = h1; o[PLANE + d] = h2; o[2 * PLANE + d] = h3;
    }
    en2h[k] = 0.5f * s;
}

// ---- prep: x (8,64,32,32) -> xs[pixel][d] bf16 x3 planes ----
__global__ void prep_x(const float* __restrict__ x, unsigned short* __restrict__ xs) {
    int p = blockIdx.x * blockDim.x + threadIdx.x;
    if (p >= Nn) return;
    int b = p >> 10, hw = p & 1023;
    unsigned short* o = xs + p * Dd;
    #pragma unroll 8
    for (int d = 0; d < Dd; ++d) {
        float v = x[(b * Dd + d) * 1024 + hw];   // coalesced across threads
        unsigned short h1, h2, h3;
        split3(v, h1, h2, h3);
        o[d] = h1; o[PLANE + d] = h2; o[2 * PLANE + d] = h3;
    }
}

// ---- fused distance GEMM (MFMA, bf16x3 exact) + partial argmin ----
// grid (Nn/64 = 128, KSPLIT), block 256 (4 waves). Wave w: pixels
// [bx*64 + w*16, +16) x codewords [by*KPB, +KPB). No LDS, no barriers.
__global__ __launch_bounds__(256) void dist_mfma(
    const unsigned short* __restrict__ xs, const unsigned short* __restrict__ es,
    const float* __restrict__ en2h,
    float* __restrict__ pval, int* __restrict__ pidx)
{
    const int tid = threadIdx.x;
    const int w = tid >> 6;
    const int lane = tid & 63;
    const int l15 = lane & 15;            // A row / B col / C col
    const int kg = lane >> 4;             // k-group (8 k's each)

    const int m0 = blockIdx.x * 64 + w * 16;
    const int n0 = blockIdx.y * KPB;

    // A fragments: pixel row = m0 + l15, k = kg*8 + j (+32 for kstep 1)
    short8 a[3][2];
    {
        const unsigned short* xp = xs + (m0 + l15) * Dd + kg * 8;
        #pragma unroll
        for (int s = 0; s < 3; ++s)
            #pragma unroll
            for (int ks = 0; ks < 2; ++ks)
                a[s][ks] = *(const short8*)(xp + s * PLANE + ks * 32);
    }

    float bv_[4]; int bi_[4];
    #pragma unroll
    for (int j = 0; j < 4; ++j) { bv_[j] = FLT_MAX; bi_[j] = 0; }

    for (int nt = 0; nt < NTILES; ++nt) {
        const int nb = n0 + nt * 16;
        const unsigned short* ep = es + (nb + l15) * Dd + kg * 8;
        short8 b0  = *(const short8*)(ep);
        short8 b0k = *(const short8*)(ep + 32);
        short8 b1  = *(const short8*)(ep + PLANE);
        short8 b1k = *(const short8*)(ep + PLANE + 32);
        short8 b2  = *(const short8*)(ep + 2 * PLANE);
        short8 b2k = *(const short8*)(ep + 2 * PLANE + 32);
        float en = en2h[nb + l15];

        f32x4 acc0 = {0.f, 0.f, 0.f, 0.f};
        f32x4 acc1 = {0.f, 0.f, 0.f, 0.f};
        // products: (0,0) + (0,1)+(1,0) + (0,2)+(1,1)+(2,0); two independent
        // accumulator chains (kstep 0/1) for pipelining
        acc0 = __builtin_amdgcn_mfma_f32_16x16x32_bf16(a[0][0], b0,  acc0, 0, 0, 0);
        acc1 = __builtin_amdgcn_mfma_f32_16x16x32_bf16(a[0][1], b0k, acc1, 0, 0, 0);
        acc0 = __builtin_amdgcn_mfma_f32_16x16x32_bf16(a[0][0], b1,  acc0, 0, 0, 0);
        acc1 = __builtin_amdgcn_mfma_f32_16x16x32_bf16(a[0][1], b1k, acc1, 0, 0, 0);
        acc0 = __builtin_amdgcn_mfma_f32_16x16x32_bf16(a[1][0], b0,  acc0, 0, 0, 0);
        acc1 = __builtin_amdgcn_mfma_f32_16x16x32_bf16(a[1][1], b0k, acc1, 0, 0, 0);
        acc0 = __builtin_amdgcn_mfma_f32_16x16x32_bf16(a[0][0], b2,  acc0, 0, 0, 0);
        acc1 = __builtin_amdgcn_mfma_f32_16x16x32_bf16(a[0][1], b2k, acc1, 0, 0, 0);
        acc0 = __builtin_amdgcn_mfma_f32_16x16x32_bf16(a[1][0], b1,  acc0, 0, 0, 0);
        acc1 = __builtin_amdgcn_mfma_f32_16x16x32_bf16(a[1][1], b1k, acc1, 0, 0, 0);
        acc0 = __builtin_amdgcn_mfma_f32_16x16x32_bf16(a[2][0], b0,  acc0, 0, 0, 0);
        acc1 = __builtin_amdgcn_mfma_f32_16x16x32_bf16(a[2][1], b0k, acc1, 0, 0, 0);

        // dist/2 = 0.5*||e||^2 - x.e  (monotone in dist); C row=(kg*4+j)=pixel
        #pragma unroll
        for (int j = 0; j < 4; ++j) {
            float d = en - (acc0[j] + acc1[j]);
            if (d < bv_[j]) { bv_[j] = d; bi_[j] = nb + l15; }
        }
    }

    // reduce across the 16 lanes of the l15 group (same kg); idx tiebreak
    #pragma unroll
    for (int m = 1; m < 16; m <<= 1) {
        #pragma unroll
        for (int j = 0; j < 4; ++j) {
            float ov = __shfl_xor(bv_[j], m, 64);
            int   oi = __shfl_xor(bi_[j], m, 64);
            if (ov < bv_[j] || (ov == bv_[j] && oi < bi_[j])) {
                bv_[j] = ov; bi_[j] = oi;
            }
        }
    }
    if (l15 == 0) {
        #pragma unroll
        for (int j = 0; j < 4; ++j) {
            int pix = m0 + kg * 4 + j;
            pval[pix * KSPLIT + blockIdx.y] = bv_[j];
            pidx[pix * KSPLIT + blockIdx.y] = bi_[j];
        }
    }
}

// ---- final argmin + gather + rotation trick ----
__global__ void finalize_kernel(
    const float* __restrict__ x, const float* __restrict__ e,
    const float* __restrict__ pval, const int* __restrict__ pidx,
    float* __restrict__ out_qd, float* __restrict__ out_q, float* __restrict__ out_ind)
{
    int n = blockIdx.x * blockDim.x + threadIdx.x;
    if (n >= Nn) return;

    float bv = FLT_MAX; int bi = 0;
    for (int s = 0; s < KSPLIT; ++s) {
        float v = pval[n * KSPLIT + s];
        int   i = pidx[n * KSPLIT + s];
        if (v < bv || (v == bv && i < bi)) { bv = v; bi = i; }
    }
    out_ind[n] = (float)bi;

    const int b = n >> 10, hw = n & 1023;
    const float* xb = x + b * (Dd * 1024) + hw;
    const float* eb = e + bi;

    float sx2 = 0.f, sq2 = 0.f, sxq = 0.f;
    #pragma unroll 8
    for (int d = 0; d < Dd; ++d) {
        float xv = xb[d * 1024];
        float qv = eb[d * Kk];
        sx2 = fmaf(xv, xv, sx2);
        sq2 = fmaf(qv, qv, sq2);
        sxq = fmaf(xv, qv, sxq);
    }
    float ne = sqrtf(sx2), nq = sqrtf(sq2);
    float inv_e = 1.f / (ne + EPS), inv_q = 1.f / (nq + EPS);
    float lmbda = (nq + EPS) * inv_e;
    float ehat_dot_e = sx2 * inv_e;
    float rn2 = sx2 * inv_e * inv_e + 2.f * sxq * inv_e * inv_q + sq2 * inv_q * inv_q;
    float inv_r = rsqrtf(rn2);
    float rde = (sx2 * inv_e + sxq * inv_q) * inv_r;

    float* qd_b = out_qd + b * (Dd * 1024) + hw;
    float* q_b  = out_q  + b * (Dd * 1024) + hw;
    #pragma unroll 8
    for (int d = 0; d < Dd; ++d) {
        float xv = xb[d * 1024];
        float qv = eb[d * Kk];
        float rv = (xv * inv_e + qv * inv_q) * inv_r;
        float qh = qv * inv_q;
        qd_b[d * 1024] = lmbda * (xv - 2.f * rv * rde + 2.f * qh * ehat_dot_e);
        q_b[d * 1024]  = qv;
    }
}

extern "C" void kernel_launch(void* const* d_in, const int* in_sizes, int n_in,
                              void* d_out, int out_size, void* d_ws, size_t ws_size,
                              hipStream_t stream) {
    const float* x = (const float*)d_in[0];   // (8,64,32,32)
    const float* e = (const float*)d_in[1];   // (64,8192)
    float* out = (float*)d_out;
    float* out_qd  = out;
    float* out_q   = out + Nn * Dd;
    float* out_ind = out + 2 * Nn * Dd;

    // ws layout: xs(3 planes bf16) | es(3 planes bf16) | en2h | pval | pidx
    unsigned short* xs = (unsigned short*)d_ws;            // 3*PLANE ushort = 3 MB
    unsigned short* es = xs + 3 * PLANE;                   // 3 MB
    float* en2h = (float*)(es + 3 * PLANE);                // 32 KB
    float* pval = en2h + Kk;                               // Nn*KSPLIT f32
    int*   pidx = (int*)(pval + Nn * KSPLIT);              // Nn*KSPLIT i32

    prep_e<<<Kk / 256, 256, 0, stream>>>(e, es, en2h);
    prep_x<<<Nn / 256, 256, 0, stream>>>(x, xs);
    dist_mfma<<<dim3(Nn / 64, KSPLIT), 256, 0, stream>>>(xs, es, en2h, pval, pidx);
    finalize_kernel<<<Nn / 256, 256, 0, stream>>>(x, e, pval, pidx, out_qd, out_q, out_ind);
}

// Round 4
// 125.114 us; speedup vs baseline: 1.8094x; 1.8094x over previous
//
#include <hip/hip_runtime.h>
#include <float.h>
#include <math.h>

#define EPS 1e-6f

typedef __attribute__((ext_vector_type(8))) short short8;   // 8 bf16 = 4 VGPR
typedef __attribute__((ext_vector_type(4))) float f32x4;

constexpr int Nn = 8192;   // B*H*W
constexpr int Dd = 64;
constexpr int Kk = 8192;
constexpr int PLANE = Nn * Dd;
constexpr int KSPLIT = 16;
constexpr int KPB = Kk / KSPLIT;          // 512 codewords per block strip
constexpr int NT = KPB / 16;              // 32 n-tiles

// exact 3-way bf16 split: v == f(h1)+f(h2)+f(h3) (24 mantissa bits, lossless)
__device__ __forceinline__ void split3(float v, unsigned short& h1, unsigned short& h2, unsigned short& h3) {
    unsigned u = __float_as_uint(v);
    h1 = (unsigned short)(u >> 16);
    float r1 = v - __uint_as_float((unsigned)h1 << 16);
    h2 = (unsigned short)(__float_as_uint(r1) >> 16);
    float r2 = r1 - __uint_as_float((unsigned)h2 << 16);
    h3 = (unsigned short)(__float_as_uint(r2) >> 16);
}

// ---- prep: e -> es planes + en2h = 0.5||e||^2 ; x -> xs planes + xn2 = ||x||^2
__global__ void prep_kernel(const float* __restrict__ e, const float* __restrict__ x,
                            unsigned short* __restrict__ es, float* __restrict__ en2h,
                            unsigned short* __restrict__ xs, float* __restrict__ xn2)
{
    const int tid = threadIdx.x;
    if (blockIdx.x < 32) {
        const int k = blockIdx.x * 256 + tid;
        float s = 0.f;
        #pragma unroll
        for (int c = 0; c < 8; ++c) {
            short8 h1v, h2v, h3v;
            #pragma unroll
            for (int j = 0; j < 8; ++j) {
                float v = e[(c * 8 + j) * Kk + k];
                s = fmaf(v, v, s);
                unsigned short h1, h2, h3; split3(v, h1, h2, h3);
                h1v[j] = (short)h1; h2v[j] = (short)h2; h3v[j] = (short)h3;
            }
            *(short8*)(es + k * Dd + c * 8) = h1v;
            *(short8*)(es + PLANE + k * Dd + c * 8) = h2v;
            *(short8*)(es + 2 * PLANE + k * Dd + c * 8) = h3v;
        }
        en2h[k] = 0.5f * s;
    } else {
        const int p = (blockIdx.x - 32) * 256 + tid;
        const int b = p >> 10, hw = p & 1023;
        float s = 0.f;
        #pragma unroll
        for (int c = 0; c < 8; ++c) {
            short8 h1v, h2v, h3v;
            #pragma unroll
            for (int j = 0; j < 8; ++j) {
                float v = x[(b * Dd + c * 8 + j) * 1024 + hw];
                s = fmaf(v, v, s);
                unsigned short h1, h2, h3; split3(v, h1, h2, h3);
                h1v[j] = (short)h1; h2v[j] = (short)h2; h3v[j] = (short)h3;
            }
            *(short8*)(xs + p * Dd + c * 8) = h1v;
            *(short8*)(xs + PLANE + p * Dd + c * 8) = h2v;
            *(short8*)(xs + 2 * PLANE + p * Dd + c * 8) = h3v;
        }
        xn2[p] = s;
    }
}

// one 16-codeword tile: 24 MFMAs (2 m-frags x 6 products x 2 ksteps) + argmin
__device__ __forceinline__ void tile_compute(
    const short8 (&a)[2][3][2], const short8 (&b)[6], float en,
    int nb, int l15, float (&bv)[2][4], int (&bi)[2][4])
{
    f32x4 acc[2][2] = {};
    // products (sx, se): (0,0),(0,1),(1,0),(0,2),(1,1),(2,0); 4 indep chains
    #define PROD(sx, se) \
        acc[0][0] = __builtin_amdgcn_mfma_f32_16x16x32_bf16(a[0][sx][0], b[(se)*2+0], acc[0][0], 0,0,0); \
        acc[1][0] = __builtin_amdgcn_mfma_f32_16x16x32_bf16(a[1][sx][0], b[(se)*2+0], acc[1][0], 0,0,0); \
        acc[0][1] = __builtin_amdgcn_mfma_f32_16x16x32_bf16(a[0][sx][1], b[(se)*2+1], acc[0][1], 0,0,0); \
        acc[1][1] = __builtin_amdgcn_mfma_f32_16x16x32_bf16(a[1][sx][1], b[(se)*2+1], acc[1][1], 0,0,0);
    PROD(0,0) PROD(0,1) PROD(1,0) PROD(0,2) PROD(1,1) PROD(2,0)
    #undef PROD
    #pragma unroll
    for (int mi = 0; mi < 2; ++mi)
        #pragma unroll
        for (int j = 0; j < 4; ++j) {
            float s = en - (acc[mi][0][j] + acc[mi][1][j]);   // 0.5||e||^2 - x.e
            if (s < bv[mi][j]) { bv[mi][j] = s; bi[mi][j] = nb + l15; }
        }
}

#define LOADB(bf, env, nbase) { \
    const unsigned short* ep_ = es + ((nbase) + l15) * Dd + kg * 8; \
    bf[0] = *(const short8*)(ep_); \
    bf[1] = *(const short8*)(ep_ + 32); \
    bf[2] = *(const short8*)(ep_ + PLANE); \
    bf[3] = *(const short8*)(ep_ + PLANE + 32); \
    bf[4] = *(const short8*)(ep_ + 2 * PLANE); \
    bf[5] = *(const short8*)(ep_ + 2 * PLANE + 32); \
    env = en2h[(nbase) + l15]; }

// grid (Nn/128 = 64, KSPLIT=16), block 256 (4 waves). Wave: 32 pixels x 512
// codewords. No LDS, no barriers; register double-buffered B prefetch.
__global__ __launch_bounds__(256) void dist_mfma(
    const unsigned short* __restrict__ xs, const unsigned short* __restrict__ es,
    const float* __restrict__ en2h,
    float* __restrict__ pval, int* __restrict__ pidx)
{
    const int tid = threadIdx.x;
    const int w = tid >> 6, lane = tid & 63;
    const int l15 = lane & 15, kg = lane >> 4;
    const int m0 = blockIdx.x * 128 + w * 32;
    const int n0 = blockIdx.y * KPB;

    // A fragments for 2 m-subtiles, resident all kernel
    short8 a[2][3][2];
    #pragma unroll
    for (int mi = 0; mi < 2; ++mi) {
        const unsigned short* xp = xs + (m0 + mi * 16 + l15) * Dd + kg * 8;
        #pragma unroll
        for (int s = 0; s < 3; ++s)
            #pragma unroll
            for (int ks = 0; ks < 2; ++ks)
                a[mi][s][ks] = *(const short8*)(xp + s * PLANE + ks * 32);
    }

    float bv[2][4]; int bi[2][4];
    #pragma unroll
    for (int mi = 0; mi < 2; ++mi)
        #pragma unroll
        for (int j = 0; j < 4; ++j) { bv[mi][j] = FLT_MAX; bi[mi][j] = 0; }

    short8 bA[6], bB[6]; float enA, enB;
    LOADB(bA, enA, n0)
    #pragma unroll 1
    for (int nt = 0; nt < NT; nt += 2) {
        const int nb = n0 + nt * 16;
        LOADB(bB, enB, nb + 16)                       // prefetch odd tile
        tile_compute(a, bA, enA, nb, l15, bv, bi);
        if (nt + 2 < NT) { LOADB(bA, enA, nb + 32) }  // prefetch next even tile
        tile_compute(a, bB, enB, nb + 16, l15, bv, bi);
    }

    // reduce across 16 codeword lanes (same kg); idx tiebreak for first-occurrence
    #pragma unroll
    for (int m = 1; m < 16; m <<= 1) {
        #pragma unroll
        for (int mi = 0; mi < 2; ++mi)
            #pragma unroll
            for (int j = 0; j < 4; ++j) {
                float ov = __shfl_xor(bv[mi][j], m, 64);
                int   oi = __shfl_xor(bi[mi][j], m, 64);
                if (ov < bv[mi][j] || (ov == bv[mi][j] && oi < bi[mi][j])) {
                    bv[mi][j] = ov; bi[mi][j] = oi;
                }
            }
    }
    if (l15 == 0) {
        #pragma unroll
        for (int mi = 0; mi < 2; ++mi)
            #pragma unroll
            for (int j = 0; j < 4; ++j) {
                int pix = m0 + mi * 16 + kg * 4 + j;
                pval[pix * KSPLIT + blockIdx.y] = bv[mi][j];
                pidx[pix * KSPLIT + blockIdx.y] = bi[mi][j];
            }
    }
}

// ---- final argmin + rotation trick (affine form qd = cx*x + cq*q) ----
// grid (32, 2): 256 pixels per block, 32 d's per blockIdx.y
__global__ __launch_bounds__(256) void finalize_kernel(
    const float* __restrict__ x, const float* __restrict__ e,
    const float* __restrict__ en2h, const float* __restrict__ xn2,
    const float* __restrict__ pval, const int* __restrict__ pidx,
    float* __restrict__ out_qd, float* __restrict__ out_q, float* __restrict__ out_ind)
{
    const int tid = threadIdx.x;
    const int p = blockIdx.x * 256 + tid;

    float bvv = FLT_MAX; int bii = 0;
    #pragma unroll
    for (int s = 0; s < KSPLIT; ++s) {
        float v = pval[p * KSPLIT + s];
        int   i = pidx[p * KSPLIT + s];
        if (v < bvv || (v == bvv && i < bii)) { bvv = v; bii = i; }
    }
    if (blockIdx.y == 0) out_ind[p] = (float)bii;

    float sx2 = xn2[p];
    float enh = en2h[bii];
    float sq2 = 2.f * enh;            // ||q||^2
    float sxq = enh - bvv;            // x.q recovered from winning score
    float ne = sqrtf(sx2), nq = sqrtf(sq2);
    float inv_e = 1.f / (ne + EPS), inv_q = 1.f / (nq + EPS);
    float lmbda = (nq + EPS) * inv_e;
    float ehat_dot_e = sx2 * inv_e;
    float rn2 = sx2 * inv_e * inv_e + 2.f * sxq * inv_e * inv_q + sq2 * inv_q * inv_q;
    float inv_r = rsqrtf(rn2);
    float rde = (sx2 * inv_e + sxq * inv_q) * inv_r;
    float cx = lmbda * (1.f - 2.f * rde * inv_r * inv_e);
    float cq = 2.f * lmbda * inv_q * (ehat_dot_e - rde * inv_r);

    const int b = p >> 10, hw = p & 1023;
    const int d0 = blockIdx.y * 32;
    const float* xb = x + (b * Dd + d0) * 1024 + hw;
    const float* ed = e + d0 * Kk + bii;
    float* qd_b = out_qd + (b * Dd + d0) * 1024 + hw;
    float* q_b  = out_q  + (b * Dd + d0) * 1024 + hw;
    #pragma unroll 4
    for (int d = 0; d < 32; ++d) {
        float xv = xb[d * 1024];          // coalesced
        float qv = ed[d * Kk];            // L2 gather
        qd_b[d * 1024] = cx * xv + cq * qv;
        q_b[d * 1024]  = qv;
    }
}

extern "C" void kernel_launch(void* const* d_in, const int* in_sizes, int n_in,
                              void* d_out, int out_size, void* d_ws, size_t ws_size,
                              hipStream_t stream) {
    const float* x = (const float*)d_in[0];   // (8,64,32,32)
    const float* e = (const float*)d_in[1];   // (64,8192)
    float* out = (float*)d_out;
    float* out_qd  = out;
    float* out_q   = out + Nn * Dd;
    float* out_ind = out + 2 * Nn * Dd;

    unsigned short* xs = (unsigned short*)d_ws;            // 3*PLANE ushort
    unsigned short* es = xs + 3 * PLANE;                   // 3*PLANE ushort
    float* en2h = (float*)(es + 3 * PLANE);                // Kk f32
    float* xn2  = en2h + Kk;                               // Nn f32
    float* pval = xn2 + Nn;                                // Nn*KSPLIT f32
    int*   pidx = (int*)(pval + Nn * KSPLIT);              // Nn*KSPLIT i32

    prep_kernel<<<64, 256, 0, stream>>>(e, x, es, en2h, xs, xn2);
    dist_mfma<<<dim3(Nn / 128, KSPLIT), 256, 0, stream>>>(xs, es, en2h, pval, pidx);
    finalize_kernel<<<dim3(32, 2), 256, 0, stream>>>(x, e, en2h, xn2, pval, pidx,
                                                     out_qd, out_q, out_ind);
}

// Round 5
// 70.555 us; speedup vs baseline: 3.2085x; 1.7733x over previous
//
#include <hip/hip_runtime.h>
#include <float.h>
#include <math.h>

#define EPS 1e-6f

typedef __attribute__((ext_vector_type(8))) short short8;   // 8 bf16 = 4 VGPR
typedef __attribute__((ext_vector_type(4))) float f32x4;

constexpr int Nn = 8192;   // B*H*W
constexpr int Dd = 64;
constexpr int Kk = 8192;
constexpr int PLANE = Nn * Dd;
constexpr int KSPLIT = 16;
constexpr int KPB = Kk / KSPLIT;          // 512 codewords per strip
constexpr int NT = KPB / 16;              // 32 tiles per strip
constexpr int TILE_USH = 6 * 64 * 8;      // 3072 ushort per 16-codeword tile

// exact 3-way bf16 split: v == f(h1)+f(h2)+f(h3) (24 mantissa bits, lossless)
__device__ __forceinline__ void split3(float v, unsigned short& h1, unsigned short& h2, unsigned short& h3) {
    unsigned u = __float_as_uint(v);
    h1 = (unsigned short)(u >> 16);
    float r1 = v - __uint_as_float((unsigned)h1 << 16);
    h2 = (unsigned short)(__float_as_uint(r1) >> 16);
    float r2 = r1 - __uint_as_float((unsigned)h2 << 16);
    h3 = (unsigned short)(__float_as_uint(r2) >> 16);
}

// ---- prep ----
// e -> es_t tiled-fragment layout + en2h + et (fp32 [k][d] transpose)
// x -> xs row-major planes + xn2
__global__ void prep_kernel(const float* __restrict__ e, const float* __restrict__ x,
                            unsigned short* __restrict__ es_t, float* __restrict__ en2h,
                            float* __restrict__ et,
                            unsigned short* __restrict__ xs, float* __restrict__ xn2)
{
    const int tid = threadIdx.x;
    if (blockIdx.x < 32) {
        const int k = blockIdx.x * 256 + tid;
        const int t = k >> 4, l15 = k & 15;
        unsigned short* tb = es_t + (size_t)t * TILE_USH;
        float s = 0.f;
        #pragma unroll
        for (int c = 0; c < 8; ++c) {          // c = ks*4 + kg ; d = c*8 + j
            const int ks = c >> 2, kg = c & 3;
            short8 h1v, h2v, h3v;
            float fv[8];
            #pragma unroll
            for (int j = 0; j < 8; ++j) {
                float v = e[(c * 8 + j) * Kk + k];
                fv[j] = v;
                s = fmaf(v, v, s);
                unsigned short h1, h2, h3; split3(v, h1, h2, h3);
                h1v[j] = (short)h1; h2v[j] = (short)h2; h3v[j] = (short)h3;
            }
            const int lofs = (kg * 16 + l15) * 8;
            *(short8*)(tb + (0 * 2 + ks) * 512 + lofs) = h1v;
            *(short8*)(tb + (1 * 2 + ks) * 512 + lofs) = h2v;
            *(short8*)(tb + (2 * 2 + ks) * 512 + lofs) = h3v;
            *(float4*)(et + (size_t)k * Dd + c * 8)     = *(float4*)&fv[0];
            *(float4*)(et + (size_t)k * Dd + c * 8 + 4) = *(float4*)&fv[4];
        }
        en2h[k] = 0.5f * s;
    } else {
        const int p = (blockIdx.x - 32) * 256 + tid;
        const int b = p >> 10, hw = p & 1023;
        float s = 0.f;
        #pragma unroll
        for (int c = 0; c < 8; ++c) {
            short8 h1v, h2v, h3v;
            #pragma unroll
            for (int j = 0; j < 8; ++j) {
                float v = x[(b * Dd + c * 8 + j) * 1024 + hw];
                s = fmaf(v, v, s);
                unsigned short h1, h2, h3; split3(v, h1, h2, h3);
                h1v[j] = (short)h1; h2v[j] = (short)h2; h3v[j] = (short)h3;
            }
            *(short8*)(xs + (size_t)p * Dd + c * 8) = h1v;
            *(short8*)(xs + PLANE + (size_t)p * Dd + c * 8) = h2v;
            *(short8*)(xs + 2 * PLANE + (size_t)p * Dd + c * 8) = h3v;
        }
        xn2[p] = s;
    }
}

// one 16-codeword tile: 24 MFMAs (2 m-frags x 6 products x 2 ksteps) + argmin
__device__ __forceinline__ void tile_compute(
    const short8 (&a)[2][3][2], const short8 (&b)[6], float en,
    int nb, int l15, float (&bv)[2][4], int (&bi)[2][4])
{
    f32x4 acc[2][2] = {};
    #define PROD(sx, se) \
        acc[0][0] = __builtin_amdgcn_mfma_f32_16x16x32_bf16(a[0][sx][0], b[(se)*2+0], acc[0][0], 0,0,0); \
        acc[1][0] = __builtin_amdgcn_mfma_f32_16x16x32_bf16(a[1][sx][0], b[(se)*2+0], acc[1][0], 0,0,0); \
        acc[0][1] = __builtin_amdgcn_mfma_f32_16x16x32_bf16(a[0][sx][1], b[(se)*2+1], acc[0][1], 0,0,0); \
        acc[1][1] = __builtin_amdgcn_mfma_f32_16x16x32_bf16(a[1][sx][1], b[(se)*2+1], acc[1][1], 0,0,0);
    PROD(0,0) PROD(0,1) PROD(1,0) PROD(0,2) PROD(1,1) PROD(2,0)
    #undef PROD
    #pragma unroll
    for (int mi = 0; mi < 2; ++mi)
        #pragma unroll
        for (int j = 0; j < 4; ++j) {
            float s = en - (acc[mi][0][j] + acc[mi][1][j]);   // 0.5||e||^2 - x.e
            if (s < bv[mi][j]) { bv[mi][j] = s; bi[mi][j] = nb + l15; }
        }
}

// coalesced tiled-fragment load: one base, imm frag offsets
#define LOADB(bf, env, ti) { \
    const short8* tp_ = (const short8*)(es_t + (size_t)(ti) * TILE_USH) + lane; \
    bf[0] = tp_[0];   bf[1] = tp_[64];  bf[2] = tp_[128]; \
    bf[3] = tp_[192]; bf[4] = tp_[256]; bf[5] = tp_[320]; \
    env = en2h[(ti) * 16 + l15]; }

// grid (Nn/128 = 64, KSPLIT=16), block 256 (4 waves). Wave: 32 pixels x 512
// codewords. No LDS/barriers; register double-buffered B prefetch.
__global__ __launch_bounds__(256, 3) void dist_mfma(
    const unsigned short* __restrict__ xs, const unsigned short* __restrict__ es_t,
    const float* __restrict__ en2h,
    float* __restrict__ pval, int* __restrict__ pidx)
{
    const int tid = threadIdx.x;
    const int w = tid >> 6, lane = tid & 63;
    const int l15 = lane & 15, kg = lane >> 4;
    const int m0 = blockIdx.x * 128 + w * 32;
    const int t0 = blockIdx.y * NT;           // first tile of this strip

    short8 a[2][3][2];
    #pragma unroll
    for (int mi = 0; mi < 2; ++mi) {
        const unsigned short* xp = xs + (size_t)(m0 + mi * 16 + l15) * Dd + kg * 8;
        #pragma unroll
        for (int s = 0; s < 3; ++s)
            #pragma unroll
            for (int ks = 0; ks < 2; ++ks)
                a[mi][s][ks] = *(const short8*)(xp + s * PLANE + ks * 32);
    }

    float bv[2][4]; int bi[2][4];
    #pragma unroll
    for (int mi = 0; mi < 2; ++mi)
        #pragma unroll
        for (int j = 0; j < 4; ++j) { bv[mi][j] = FLT_MAX; bi[mi][j] = 0; }

    short8 bA[6], bB[6]; float enA, enB;
    LOADB(bA, enA, t0)
    #pragma unroll 1
    for (int nt = 0; nt < NT; nt += 2) {
        const int ti = t0 + nt;
        LOADB(bB, enB, ti + 1)                        // prefetch odd tile
        tile_compute(a, bA, enA, ti * 16, l15, bv, bi);
        if (nt + 2 < NT) { LOADB(bA, enA, ti + 2) }   // prefetch next even tile
        tile_compute(a, bB, enB, ti * 16 + 16, l15, bv, bi);
    }

    #pragma unroll
    for (int m = 1; m < 16; m <<= 1) {
        #pragma unroll
        for (int mi = 0; mi < 2; ++mi)
            #pragma unroll
            for (int j = 0; j < 4; ++j) {
                float ov = __shfl_xor(bv[mi][j], m, 64);
                int   oi = __shfl_xor(bi[mi][j], m, 64);
                if (ov < bv[mi][j] || (ov == bv[mi][j] && oi < bi[mi][j])) {
                    bv[mi][j] = ov; bi[mi][j] = oi;
                }
            }
    }
    if (l15 == 0) {
        #pragma unroll
        for (int mi = 0; mi < 2; ++mi)
            #pragma unroll
            for (int j = 0; j < 4; ++j) {
                int pix = m0 + mi * 16 + kg * 4 + j;
                pval[pix * KSPLIT + blockIdx.y] = bv[mi][j];
                pidx[pix * KSPLIT + blockIdx.y] = bi[mi][j];
            }
    }
}

// ---- final argmin + rotation trick (affine form qd = cx*x + cq*q) ----
// grid (32, 2): 256 pixels per block, 32 d's per blockIdx.y
__global__ __launch_bounds__(256) void finalize_kernel(
    const float* __restrict__ x, const float* __restrict__ et,
    const float* __restrict__ en2h, const float* __restrict__ xn2,
    const float* __restrict__ pval, const int* __restrict__ pidx,
    float* __restrict__ out_qd, float* __restrict__ out_q, float* __restrict__ out_ind)
{
    const int tid = threadIdx.x;
    const int p = blockIdx.x * 256 + tid;

    float bvv = FLT_MAX; int bii = 0;
    #pragma unroll
    for (int s = 0; s < KSPLIT; ++s) {
        float v = pval[p * KSPLIT + s];
        int   i = pidx[p * KSPLIT + s];
        if (v < bvv || (v == bvv && i < bii)) { bvv = v; bii = i; }
    }
    if (blockIdx.y == 0) out_ind[p] = (float)bii;

    float sx2 = xn2[p];
    float enh = en2h[bii];
    float sq2 = 2.f * enh;            // ||q||^2
    float sxq = enh - bvv;            // x.q recovered from winning score
    float ne = sqrtf(sx2), nq = sqrtf(sq2);
    float inv_e = 1.f / (ne + EPS), inv_q = 1.f / (nq + EPS);
    float lmbda = (nq + EPS) * inv_e;
    float ehat_dot_e = sx2 * inv_e;
    float rn2 = sx2 * inv_e * inv_e + 2.f * sxq * inv_e * inv_q + sq2 * inv_q * inv_q;
    float inv_r = rsqrtf(rn2);
    float rde = (sx2 * inv_e + sxq * inv_q) * inv_r;
    float cx = lmbda * (1.f - 2.f * rde * inv_r * inv_e);
    float cq = 2.f * lmbda * inv_q * (ehat_dot_e - rde * inv_r);

    const int b = p >> 10, hw = p & 1023;
    const int d0 = blockIdx.y * 32;
    const float* xb = x + (b * Dd + d0) * 1024 + hw;
    const float* er = et + (size_t)bii * Dd + d0;   // consecutive per thread
    float* qd_b = out_qd + (b * Dd + d0) * 1024 + hw;
    float* q_b  = out_q  + (b * Dd + d0) * 1024 + hw;
    #pragma unroll
    for (int dv = 0; dv < 8; ++dv) {
        float4 q4 = *(const float4*)(er + dv * 4);
        #pragma unroll
        for (int jj = 0; jj < 4; ++jj) {
            int d = dv * 4 + jj;
            float xv = xb[d * 1024];
            float qv = ((const float*)&q4)[jj];
            qd_b[d * 1024] = cx * xv + cq * qv;
            q_b[d * 1024]  = qv;
        }
    }
}

extern "C" void kernel_launch(void* const* d_in, const int* in_sizes, int n_in,
                              void* d_out, int out_size, void* d_ws, size_t ws_size,
                              hipStream_t stream) {
    const float* x = (const float*)d_in[0];   // (8,64,32,32)
    const float* e = (const float*)d_in[1];   // (64,8192)
    float* out = (float*)d_out;
    float* out_qd  = out;
    float* out_q   = out + Nn * Dd;
    float* out_ind = out + 2 * Nn * Dd;

    unsigned short* xs   = (unsigned short*)d_ws;          // 3*PLANE ushort (3 MB)
    unsigned short* es_t = xs + 3 * PLANE;                 // 512*3072 ushort (3 MB)
    float* et   = (float*)(es_t + (size_t)(Kk / 16) * TILE_USH);  // Kk*Dd f32 (2 MB)
    float* en2h = et + (size_t)Kk * Dd;                    // Kk f32
    float* xn2  = en2h + Kk;                               // Nn f32
    float* pval = xn2 + Nn;                                // Nn*KSPLIT f32
    int*   pidx = (int*)(pval + Nn * KSPLIT);              // Nn*KSPLIT i32

    prep_kernel<<<64, 256, 0, stream>>>(e, x, es_t, en2h, et, xs, xn2);
    dist_mfma<<<dim3(Nn / 128, KSPLIT), 256, 0, stream>>>(xs, es_t, en2h, pval, pidx);
    finalize_kernel<<<dim3(32, 2), 256, 0, stream>>>(x, et, en2h, xn2, pval, pidx,
                                                     out_qd, out_q, out_ind);
}